// Round 1
// baseline (104.585 us; speedup 1.0000x reference)
//
#include <hip/hip_runtime.h>

// DotPred: score[t,e] = sum_d (x[src[t,e],d] - x[dst[t,e],d]) / sqrt(D)
//        = (rowsum(x)[src] - rowsum(x)[dst]) * (1/sqrt(D))
// Two-phase: (1) per-node rowsum into d_ws, (2) per-edge gather/subtract.
// Indices arrive as int32 (JAX x64 disabled; harness: integer -> const int*).
//
// R6 post-mortem: cooperative grid.sync() fusion cost ~130us of barrier spin
// (8 non-coherent XCDs) vs ~4us of dispatch gap — reverted to two launches.
// Nontemporal hints (R5) measured neutral — S is not L2-thrashed. Plain loads.
// R7: prior bench core-dumped with no counters (GPU-fault signature or infra
// flake). Hardened: (a) index clamp in edge kernels so corrupt indices give a
// reportable absmax instead of an abort; (b) fused no-workspace fallback if
// ws_size < n_nodes*4 (the only kernel-side fault candidate). Normal path
// is unchanged.

#define IN_DIM 128
#define INV_SQRT_D 0.08838834764831843f  // 1/sqrt(128)

__device__ __forceinline__ int clamp_idx(int v, int n) {
    return ((unsigned)v < (unsigned)n) ? v : 0;
}

// 32 lanes per row (float4 each = 128 floats), 2 rows per wave, 8 rows per 256-block.
__global__ void rowsum_kernel(const float4* __restrict__ x4,
                              float* __restrict__ S, int n_nodes) {
    const int wave = (blockIdx.x * blockDim.x + threadIdx.x) >> 6;
    const int lane = threadIdx.x & 63;
    const int row  = wave * 2 + (lane >> 5);
    if (row >= n_nodes) return;
    const int col = lane & 31;

    const float4 v = x4[(size_t)row * (IN_DIM / 4) + col];
    float s = (v.x + v.y) + (v.z + v.w);

    // Butterfly within each 32-lane half (xor of bits 0..4 stays in-half).
    #pragma unroll
    for (int off = 16; off > 0; off >>= 1)
        s += __shfl_xor(s, off, 64);

    if (col == 0) S[row] = s;   // lanes 0 and 32 write their rows
}

// 4 edges per thread: int4 index loads, float4 store.
__global__ void edge_kernel4(const int4* __restrict__ src4,
                             const int4* __restrict__ dst4,
                             const float* __restrict__ S,
                             float4* __restrict__ out4, int n4, int n_nodes) {
    const int i = blockIdx.x * blockDim.x + threadIdx.x;
    if (i >= n4) return;
    int4 s = src4[i];
    int4 d = dst4[i];
    s.x = clamp_idx(s.x, n_nodes); s.y = clamp_idx(s.y, n_nodes);
    s.z = clamp_idx(s.z, n_nodes); s.w = clamp_idx(s.w, n_nodes);
    d.x = clamp_idx(d.x, n_nodes); d.y = clamp_idx(d.y, n_nodes);
    d.z = clamp_idx(d.z, n_nodes); d.w = clamp_idx(d.w, n_nodes);
    float4 o;
    o.x = (S[s.x] - S[d.x]) * INV_SQRT_D;
    o.y = (S[s.y] - S[d.y]) * INV_SQRT_D;
    o.z = (S[s.z] - S[d.z]) * INV_SQRT_D;
    o.w = (S[s.w] - S[d.w]) * INV_SQRT_D;
    out4[i] = o;
}

// Scalar tail (n % 4 != 0) — never triggers for n=1.5M but kept for robustness.
__global__ void edge_kernel_tail(const int* __restrict__ src,
                                 const int* __restrict__ dst,
                                 const float* __restrict__ S,
                                 float* __restrict__ out, int start, int n,
                                 int n_nodes) {
    const int i = start + blockIdx.x * blockDim.x + threadIdx.x;
    if (i >= n) return;
    out[i] = (S[clamp_idx(src[i], n_nodes)] - S[clamp_idx(dst[i], n_nodes)]) * INV_SQRT_D;
}

// Emergency fallback if workspace is insufficient: fused gather, one thread
// per edge, no scratch needed. ~6x slower than the two-phase path but correct.
__global__ void fused_edge_kernel(const float4* __restrict__ x4,
                                  const int* __restrict__ src,
                                  const int* __restrict__ dst,
                                  float* __restrict__ out,
                                  int n_edges, int n_nodes) {
    const int e = blockIdx.x * blockDim.x + threadIdx.x;
    if (e >= n_edges) return;
    const int s = clamp_idx(src[e], n_nodes);
    const int d = clamp_idx(dst[e], n_nodes);
    const float4* xs = x4 + (size_t)s * (IN_DIM / 4);
    const float4* xd = x4 + (size_t)d * (IN_DIM / 4);
    float acc = 0.0f;
    #pragma unroll
    for (int c = 0; c < IN_DIM / 4; ++c) {
        const float4 a = xs[c];
        const float4 b = xd[c];
        acc += (a.x - b.x) + (a.y - b.y) + (a.z - b.z) + (a.w - b.w);
    }
    out[e] = acc * INV_SQRT_D;
}

extern "C" void kernel_launch(void* const* d_in, const int* in_sizes, int n_in,
                              void* d_out, int out_size, void* d_ws, size_t ws_size,
                              hipStream_t stream) {
    const float* x   = (const float*)d_in[0];
    const int*   src = (const int*)d_in[1];
    const int*   dst = (const int*)d_in[2];
    float* out = (float*)d_out;
    float* S   = (float*)d_ws;   // n_nodes floats of scratch (400 KB)

    const int n_nodes = in_sizes[0] / IN_DIM;   // 100000
    const int n_edges = in_sizes[1];            // T*E = 1.5M

    if (ws_size < (size_t)n_nodes * sizeof(float)) {
        // Workspace too small for the rowsum table — fused fallback.
        const int grid = (n_edges + 255) / 256;
        fused_edge_kernel<<<grid, 256, 0, stream>>>((const float4*)x, src, dst,
                                                    out, n_edges, n_nodes);
        return;
    }

    // Phase 1: rowsums. 8 rows per 256-thread block.
    const int grid1 = (n_nodes + 7) / 8;
    rowsum_kernel<<<grid1, 256, 0, stream>>>((const float4*)x, S, n_nodes);

    // Phase 2: edge scores, 4 per thread.
    const int n4 = n_edges >> 2;
    if (n4 > 0) {
        const int grid2 = (n4 + 255) / 256;
        edge_kernel4<<<grid2, 256, 0, stream>>>((const int4*)src, (const int4*)dst,
                                                S, (float4*)out, n4, n_nodes);
    }
    const int tail_start = n4 << 2;
    const int tail = n_edges - tail_start;
    if (tail > 0) {
        edge_kernel_tail<<<1, 256, 0, stream>>>(src, dst, S, out, tail_start,
                                                n_edges, n_nodes);
    }
}